// Round 1
// baseline (1140.940 us; speedup 1.0000x reference)
//
#include <hip/hip_runtime.h>

#define NUM_E   16384
#define DIM     256
#define NROWS   8192      // B*H*W = 8*32*32
#define HW      1024      // H*W
#define NSPLIT  8
#define KSPAN   (NUM_E / NSPLIT)   // 2048

// ---------------- K1: inverse norms of embedding rows ----------------
__global__ void k_inv_e(const float* __restrict__ emb, float* __restrict__ inv_e) {
    int w = threadIdx.x >> 6;          // wave within block (0..3)
    int lane = threadIdx.x & 63;
    int k = blockIdx.x * 4 + w;        // grid 4096 -> 16384 rows
    float4 v = *(const float4*)(emb + (size_t)k * DIM + lane * 4);
    float s = v.x*v.x + v.y*v.y + v.z*v.z + v.w*v.w;
    for (int off = 32; off > 0; off >>= 1) s += __shfl_down(s, off);
    if (lane == 0) inv_e[k] = 1.0f / fmaxf(sqrtf(s), 1e-12f);
}

// ---------------- K2: normalized transpose embT[d][k] ----------------
__global__ void k_embT(const float* __restrict__ emb, const float* __restrict__ inv_e,
                       float* __restrict__ embT) {
    __shared__ float T[64 * 68];       // 64 rows x 64 dims, pad stride 68
    int k0 = blockIdx.x * 64, d0 = blockIdx.y * 64;
    int t = threadIdx.x;
    #pragma unroll
    for (int i = 0; i < 4; i++) {
        int f = t + 256 * i;           // float4 tile index 0..1023
        int kk = f >> 4, d4 = (f & 15) * 4;
        float inv = inv_e[k0 + kk];
        float4 v = *(const float4*)(emb + (size_t)(k0 + kk) * DIM + d0 + d4);
        v.x *= inv; v.y *= inv; v.z *= inv; v.w *= inv;
        *(float4*)&T[kk * 68 + d4] = v;
    }
    __syncthreads();
    #pragma unroll
    for (int i = 0; i < 4; i++) {
        int f = t + 256 * i;
        int dd = f >> 4, k4 = (f & 15) * 4;
        float4 o;
        o.x = T[(k4 + 0) * 68 + dd];
        o.y = T[(k4 + 1) * 68 + dd];
        o.z = T[(k4 + 2) * 68 + dd];
        o.w = T[(k4 + 3) * 68 + dd];
        *(float4*)(embT + (size_t)(d0 + dd) * NUM_E + k0 + k4) = o;
    }
}

// ---------------- K3: inverse norms of z rows (z is [B,C,H,W]) ----------------
__global__ void k_inv_z(const float* __restrict__ z, float* __restrict__ inv_z) {
    int n = blockIdx.x * 256 + threadIdx.x;   // grid 32 -> 8192
    int b = n >> 10, hw = n & 1023;
    const float* p = z + (size_t)b * DIM * HW + hw;
    float s = 0.f;
    #pragma unroll 8
    for (int c = 0; c < DIM; c++) { float v = p[c * HW]; s += v * v; }
    inv_z[n] = 1.0f / fmaxf(sqrtf(s), 1e-12f);
}

// ---------------- K5: fp32 GEMM + per-row top-2 tracking ----------------
// grid (NSPLIT, 128); block tile 64 rows x 64 cols; 4x4 microtile
__launch_bounds__(256)
__global__ void k_score(const float* __restrict__ z, const float* __restrict__ embT,
                        const float* __restrict__ inv_z, float4* __restrict__ part) {
    __shared__ float Zs[DIM * 64];   // 64 KB, [c][m] full-depth Z tile
    __shared__ float Es[64 * 64];    // 16 KB, [d][k] chunk (reused as reduce buffer)
    int t = threadIdx.x, tx = t & 15, ty = t >> 4;
    int split = blockIdx.x;
    int m0 = blockIdx.y * 64;
    int b = m0 >> 10, hw0 = m0 & 1023;     // 64 rows stay within one b

    // stage full-depth Z tile, normalized on the fly
    #pragma unroll
    for (int i = 0; i < 16; i++) {
        int f = t + 256 * i;               // float4 index 0..4095
        int c = f >> 4, m4 = (f & 15) * 4;
        float4 v  = *(const float4*)(z + (size_t)(b * DIM + c) * HW + hw0 + m4);
        float4 iv = *(const float4*)(inv_z + m0 + m4);
        v.x *= iv.x; v.y *= iv.y; v.z *= iv.z; v.w *= iv.w;
        *(float4*)&Zs[c * 64 + m4] = v;
    }
    float v1[4], v2[4]; int i1[4], i2[4];
    #pragma unroll
    for (int i = 0; i < 4; i++) { v1[i] = -2e9f; v2[i] = -2e9f; i1[i] = 0; i2[i] = 0; }
    __syncthreads();

    for (int kt = 0; kt < KSPAN / 64; kt++) {
        int k0 = split * KSPAN + kt * 64;
        float acc[4][4] = {};
        for (int dc = 0; dc < DIM; dc += 64) {
            #pragma unroll
            for (int i = 0; i < 4; i++) {
                int f = t + 256 * i;       // 0..1023
                int d = f >> 4, k4 = (f & 15) * 4;
                *(float4*)&Es[d * 64 + k4] =
                    *(const float4*)(embT + (size_t)(dc + d) * NUM_E + k0 + k4);
            }
            __syncthreads();
            #pragma unroll 8
            for (int d = 0; d < 64; d++) {
                float4 a  = *(float4*)&Zs[(dc + d) * 64 + 4 * ty];
                float4 bb = *(float4*)&Es[d * 64 + 4 * tx];
                float av[4] = {a.x, a.y, a.z, a.w};
                float bv[4] = {bb.x, bb.y, bb.z, bb.w};
                #pragma unroll
                for (int i = 0; i < 4; i++)
                    #pragma unroll
                    for (int j = 0; j < 4; j++)
                        acc[i][j] = fmaf(av[i], bv[j], acc[i][j]);
            }
            __syncthreads();
        }
        // per-thread top-2 update (k ascending per thread -> strict > keeps first index)
        #pragma unroll
        for (int j = 0; j < 4; j++) {
            int k = k0 + 4 * tx + j;
            #pragma unroll
            for (int i = 0; i < 4; i++) {
                float s = acc[i][j];
                if (s > v1[i])      { v2[i] = v1[i]; i2[i] = i1[i]; v1[i] = s; i1[i] = k; }
                else if (s > v2[i]) { v2[i] = s; i2[i] = k; }
            }
        }
    }
    __syncthreads();
    // cross-thread top-2 merge via LDS (reuse Es: 64 rows x 16 tx x 16B = 16 KB)
    float4* red = (float4*)Es;
    #pragma unroll
    for (int i = 0; i < 4; i++)
        red[(4 * ty + i) * 16 + tx] =
            make_float4(v1[i], __int_as_float(i1[i]), v2[i], __int_as_float(i2[i]));
    __syncthreads();
    if (t < 64) {
        float V1 = -2e9f, V2 = -2e9f; int I1 = 0, I2 = 0;
        for (int x = 0; x < 16; x++) {
            float4 e = red[t * 16 + x];
            float cv1 = e.x; int ci1 = __float_as_int(e.y);
            float cv2 = e.z; int ci2 = __float_as_int(e.w);
            if (cv1 > V1 || (cv1 == V1 && ci1 < I1)) { V2 = V1; I2 = I1; V1 = cv1; I1 = ci1; }
            else if (cv1 > V2 || (cv1 == V2 && ci1 < I2)) { V2 = cv1; I2 = ci1; }
            if (cv2 > V2 || (cv2 == V2 && ci2 < I2)) { V2 = cv2; I2 = ci2; }
        }
        part[(size_t)split * NROWS + m0 + t] =
            make_float4(V1, __int_as_float(I1), V2, __int_as_float(I2));
    }
}

// ---------------- K6: cross-split reduce + fp64 rescore of near-ties ----------------
__global__ void k_final(const float4* __restrict__ part, const float* __restrict__ z,
                        const float* __restrict__ emb, int* __restrict__ idx_ws,
                        float* __restrict__ out_idx) {
    int n = blockIdx.x * 256 + threadIdx.x;   // grid 32
    float V1 = -2e9f, V2 = -2e9f; int I1 = 0, I2 = 0;
    for (int s = 0; s < NSPLIT; s++) {
        float4 e = part[(size_t)s * NROWS + n];
        float cv1 = e.x; int ci1 = __float_as_int(e.y);
        float cv2 = e.z; int ci2 = __float_as_int(e.w);
        if (cv1 > V1 || (cv1 == V1 && ci1 < I1)) { V2 = V1; I2 = I1; V1 = cv1; I1 = ci1; }
        else if (cv1 > V2 || (cv1 == V2 && ci1 < I2)) { V2 = cv1; I2 = ci1; }
        if (cv2 > V2 || (cv2 == V2 && ci2 < I2)) { V2 = cv2; I2 = ci2; }
    }
    int best = I1;
    if (V1 - V2 < 1e-4f) {
        // exact fp64 rescore from RAW inputs (renormalize in fp64)
        int b = n >> 10, hw = n & 1023;
        const float* zp = z + (size_t)b * DIM * HW + hw;
        const float* e1 = emb + (size_t)I1 * DIM;
        const float* e2 = emb + (size_t)I2 * DIM;
        double sz = 0, d1 = 0, d2 = 0, s1e = 0, s2e = 0;
        for (int c = 0; c < DIM; c++) {
            double zv = (double)zp[c * HW];
            double a1 = (double)e1[c], a2 = (double)e2[c];
            sz += zv * zv; d1 += zv * a1; d2 += zv * a2;
            s1e += a1 * a1; s2e += a2 * a2;
        }
        double q1 = d1 / (sqrt(sz) * sqrt(s1e));
        double q2 = d2 / (sqrt(sz) * sqrt(s2e));
        best = (q2 > q1 || (q2 == q1 && I2 < I1)) ? I2 : I1;
    }
    idx_ws[n] = best;
    out_idx[n] = (float)best;   // harness reads d_out as float32
}

// ---------------- K7: gather z_q[b][c][hw] = embT[c][idx[n]] ----------------
__global__ void k_zq(const int* __restrict__ idx_ws, const float* __restrict__ embT,
                     float* __restrict__ zq) {
    int bc = blockIdx.x;                // grid 2048 = b*256 + c
    int b = bc >> 8, c = bc & 255;
    int t = threadIdx.x;
    int hw = t * 4;
    int4 id = *(const int4*)(idx_ws + b * HW + hw);
    const float* row = embT + (size_t)c * NUM_E;
    float4 o = make_float4(row[id.x], row[id.y], row[id.z], row[id.w]);
    *(float4*)(zq + (size_t)bc * HW + hw) = o;
}

extern "C" void kernel_launch(void* const* d_in, const int* in_sizes, int n_in,
                              void* d_out, int out_size, void* d_ws, size_t ws_size,
                              hipStream_t stream) {
    const float* z   = (const float*)d_in[0];   // [8,256,32,32]
    const float* emb = (const float*)d_in[1];   // [16384,256]
    float* ws = (float*)d_ws;
    // ws layout (floats): embT 4194304 | inv_e 16384 | inv_z 8192 | part 262144 | idx 8192
    float*  embT   = ws;
    float*  inv_e  = ws + 4194304;
    float*  inv_z  = inv_e + NUM_E;
    float4* part   = (float4*)(inv_z + NROWS);
    int*    idx_ws = (int*)((float*)part + (size_t)NSPLIT * NROWS * 4);
    float*  zq      = (float*)d_out;            // 2097152 floats
    float*  out_idx = zq + (size_t)NROWS * DIM; // 8192 floats (indices as float)

    k_inv_e <<<4096, 256, 0, stream>>>(emb, inv_e);
    k_embT  <<<dim3(NUM_E / 64, DIM / 64), 256, 0, stream>>>(emb, inv_e, embT);
    k_inv_z <<<NROWS / 256, 256, 0, stream>>>(z, inv_z);
    k_score <<<dim3(NSPLIT, NROWS / 64), 256, 0, stream>>>(z, embT, inv_z, part);
    k_final <<<NROWS / 256, 256, 0, stream>>>(part, z, emb, idx_ws, out_idx);
    k_zq    <<<2048, 256, 0, stream>>>(idx_ws, embT, zq);
}